// Round 12
// baseline (206.481 us; speedup 1.0000x reference)
//
#include <hip/hip_runtime.h>
#include <math.h>

#define G      1708
#define GP     1728         // padded per-head row stride
#define C4     427          // float4 chunks per row
#define NH     5
#define NB     16
#define NC     34
#define JSL    16           // j-slices per i-group
#define ITR    2            // i per thread
#define IPB    32           // i per block = (256/JSL)*ITR
#define ICH    54           // ceil(G/IPB)
#define LN_EPS 1e-6f
#define LOG2E  1.4426950408889634f

// ---------------------------------------------------------------------------
// Rank-1 score: s_ij = q_i*k_j => exact row max m_i = max(q_i*kmax, q_i*kmin).
// Per layer:
//   build_layer (grid 5x16): combine prev heads + LN ONCE -> q/k(log2)/v
//     tables (global, GP stride) + kmin/kmax + combined h row.
//   attn_layer (grid 54x5x16): stage k/v row -> LDS, j-loop, per-head out.
// ---------------------------------------------------------------------------

template <bool FIRST>
__global__ __launch_bounds__(256) void build_layer(
    const float* __restrict__ hprev, const float* __restrict__ php,
    const float* __restrict__ lna, const float* __restrict__ lnb,
    const float* __restrict__ WQ, const float* __restrict__ WK,
    const float* __restrict__ WV,
    float* __restrict__ qt, float* __restrict__ kt, float* __restrict__ vt,
    float* __restrict__ kmm, float* __restrict__ hcur)
{
    __shared__ __align__(16) float arow[G];
    __shared__ float red[8];
    const int h = blockIdx.x, b = blockIdx.y, tid = threadIdx.x;

    const float4* hp4 = reinterpret_cast<const float4*>(hprev + (size_t)b * G);
    float4* ar4 = reinterpret_cast<float4*>(arow);

    float mean = 0.f, inv = 0.f;
    if constexpr (!FIRST) {
        const float4* p0 = reinterpret_cast<const float4*>(php + ((size_t)b * NH + 0) * GP);
        const float4* p1 = reinterpret_cast<const float4*>(php + ((size_t)b * NH + 1) * GP);
        const float4* p2 = reinterpret_cast<const float4*>(php + ((size_t)b * NH + 2) * GP);
        const float4* p3 = reinterpret_cast<const float4*>(php + ((size_t)b * NH + 3) * GP);
        const float4* p4 = reinterpret_cast<const float4*>(php + ((size_t)b * NH + 4) * GP);
        float s = 0.f, ss = 0.f;
        for (int c = tid; c < C4; c += 256) {
            float4 a = p0[c], t;
            t = p1[c]; a.x += t.x; a.y += t.y; a.z += t.z; a.w += t.w;
            t = p2[c]; a.x += t.x; a.y += t.y; a.z += t.z; a.w += t.w;
            t = p3[c]; a.x += t.x; a.y += t.y; a.z += t.z; a.w += t.w;
            t = p4[c]; a.x += t.x; a.y += t.y; a.z += t.z; a.w += t.w;
            ar4[c] = a;
            s  += (a.x + a.y) + (a.z + a.w);
            ss += (a.x * a.x + a.y * a.y) + (a.z * a.z + a.w * a.w);
        }
        for (int o = 1; o < 64; o <<= 1) {
            s  += __shfl_xor(s, o);
            ss += __shfl_xor(ss, o);
        }
        if ((tid & 63) == 0) { red[tid >> 6] = s; red[4 + (tid >> 6)] = ss; }
        __syncthreads();
        float S  = (red[0] + red[1]) + (red[2] + red[3]);
        float SS = (red[4] + red[5]) + (red[6] + red[7]);
        mean = S / (float)G;
        float var = fmaxf((SS - S * mean) / (float)(G - 1), 0.f);
        inv = 1.f / (sqrtf(var) + LN_EPS);
    }

    const float4* wq4 = reinterpret_cast<const float4*>(WQ + (size_t)h * G);
    const float4* wk4 = reinterpret_cast<const float4*>(WK + (size_t)h * G);
    const float4* wv4 = reinterpret_cast<const float4*>(WV + (size_t)h * G);
    const float4* ga4 = reinterpret_cast<const float4*>(lna);
    const float4* gb4 = reinterpret_cast<const float4*>(lnb);
    const size_t bh = (size_t)(b * NH + h) * GP;
    float4* qo = reinterpret_cast<float4*>(qt + bh);
    float4* ko = reinterpret_cast<float4*>(kt + bh);
    float4* vo = reinterpret_cast<float4*>(vt + bh);
    float4* hc4 = (hcur != nullptr) ? reinterpret_cast<float4*>(hcur + (size_t)b * G)
                                    : nullptr;

    float kmx = -INFINITY, kmn = INFINITY;
    for (int c = tid; c < C4; c += 256) {
        float4 hv;
        if constexpr (FIRST) {
            hv = hp4[c];
        } else {
            float4 a = ar4[c], hp = hp4[c], ga = ga4[c], gb = gb4[c];
            hv.x = hp.x + ga.x * (a.x - mean) * inv + gb.x;
            hv.y = hp.y + ga.y * (a.y - mean) * inv + gb.y;
            hv.z = hp.z + ga.z * (a.z - mean) * inv + gb.z;
            hv.w = hp.w + ga.w * (a.w - mean) * inv + gb.w;
        }
        float4 wq = wq4[c], wk = wk4[c], wv = wv4[c], kl, vv, qq;
        qq.x = hv.x * wq.x; qq.y = hv.y * wq.y;
        qq.z = hv.z * wq.z; qq.w = hv.w * wq.w;
        kl.x = hv.x * wk.x * LOG2E; kl.y = hv.y * wk.y * LOG2E;
        kl.z = hv.z * wk.z * LOG2E; kl.w = hv.w * wk.w * LOG2E;
        vv.x = hv.x * wv.x; vv.y = hv.y * wv.y;
        vv.z = hv.z * wv.z; vv.w = hv.w * wv.w;
        qo[c] = qq;
        ko[c] = kl;
        vo[c] = vv;
        if (!FIRST && h == 0 && hc4 != nullptr) hc4[c] = hv;
        kmx = fmaxf(kmx, fmaxf(fmaxf(kl.x, kl.y), fmaxf(kl.z, kl.w)));
        kmn = fminf(kmn, fminf(fminf(kl.x, kl.y), fminf(kl.z, kl.w)));
    }
    for (int o = 1; o < 64; o <<= 1) {
        kmx = fmaxf(kmx, __shfl_xor(kmx, o));
        kmn = fminf(kmn, __shfl_xor(kmn, o));
    }
    __syncthreads();
    if ((tid & 63) == 0) { red[tid >> 6] = kmx; red[4 + (tid >> 6)] = kmn; }
    __syncthreads();
    if (tid == 0) {
        kmx = fmaxf(fmaxf(red[0], red[1]), fmaxf(red[2], red[3]));
        kmn = fminf(fminf(red[4], red[5]), fminf(red[6], red[7]));
        kmm[(b * NH + h) * 2 + 0] = kmx;
        kmm[(b * NH + h) * 2 + 1] = kmn;
    }
}

// ---------------------------------------------------------------------------
// attn_layer: stage k/v row -> LDS; j-loop; per-head output.
// grid (54,5,16)=4320, 256 thr, 13.7 KB LDS -> 8 blocks/CU (wave cap).
// ---------------------------------------------------------------------------
__global__ __launch_bounds__(256) void attn_layer(
    const float* __restrict__ qt, const float* __restrict__ kt,
    const float* __restrict__ vt, const float* __restrict__ kmm,
    const float* __restrict__ W0, float* __restrict__ ph)
{
    __shared__ __align__(16) float krow[G];
    __shared__ __align__(16) float vrow[G];

    const int ic = blockIdx.x, h = blockIdx.y, b = blockIdx.z;
    const int tid = threadIdx.x;
    const size_t bh = (size_t)(b * NH + h) * GP;

    const float4* kg4 = reinterpret_cast<const float4*>(kt + bh);
    const float4* vg4 = reinterpret_cast<const float4*>(vt + bh);
    float4* kr4 = reinterpret_cast<float4*>(krow);
    float4* vr4 = reinterpret_cast<float4*>(vrow);
    for (int c = tid; c < C4; c += 256) {
        kr4[c] = kg4[c];
        vr4[c] = vg4[c];
    }

    const float kmx = kmm[(b * NH + h) * 2 + 0];
    const float kmn = kmm[(b * NH + h) * 2 + 1];

    const int ig = tid >> 4, sl = tid & 15;
    const int i0 = ic * IPB + ig * ITR;      // even
    const bool valid = i0 < G;               // G even; i0+1 <= 1707
    const int is = valid ? i0 : 0;

    const float2 q2 = *reinterpret_cast<const float2*>(qt + bh + is);
    float q[ITR] = {q2.x, q2.y};
    float m[ITR], S1[ITR], S2[ITR];
#pragma unroll
    for (int r = 0; r < ITR; ++r) {
        m[r]  = fmaxf(q[r] * kmx, q[r] * kmn);
        S1[r] = 0.f;
        S2[r] = 0.f;
    }
    __syncthreads();

#pragma unroll 2
    for (int c = sl; c < C4; c += JSL) {
        float4 kk = kr4[c];
        float4 vq = vr4[c];
#pragma unroll
        for (int r = 0; r < ITR; ++r) {
            float qq = q[r], mm = m[r];
            float e0 = __builtin_amdgcn_exp2f(fmaf(qq, kk.x, -mm));
            float e1 = __builtin_amdgcn_exp2f(fmaf(qq, kk.y, -mm));
            float e2 = __builtin_amdgcn_exp2f(fmaf(qq, kk.z, -mm));
            float e3 = __builtin_amdgcn_exp2f(fmaf(qq, kk.w, -mm));
            S1[r] += (e0 + e1) + (e2 + e3);
            S2[r] += (e0 * vq.x + e1 * vq.y) + (e2 * vq.z + e3 * vq.w);
        }
    }

#pragma unroll
    for (int r = 0; r < ITR; ++r) {
        S1[r] += __shfl_xor(S1[r], 1);
        S1[r] += __shfl_xor(S1[r], 2);
        S1[r] += __shfl_xor(S1[r], 4);
        S1[r] += __shfl_xor(S1[r], 8);
        S2[r] += __shfl_xor(S2[r], 1);
        S2[r] += __shfl_xor(S2[r], 2);
        S2[r] += __shfl_xor(S2[r], 4);
        S2[r] += __shfl_xor(S2[r], 8);
    }

    if (sl == 0 && valid) {
        const float w0h = W0[h];
        const float2* kr2 = reinterpret_cast<const float2*>(krow);
        const float2* vr2 = reinterpret_cast<const float2*>(vrow);
        const float2 kt2 = kr2[i0 >> 1];
        const float2 vt2 = vr2[i0 >> 1];
        const float kli[ITR] = {kt2.x, kt2.y};
        const float vvi[ITR] = {vt2.x, vt2.y};
        float o[ITR];
#pragma unroll
        for (int r = 0; r < ITR; ++r) {
            float eii = __builtin_amdgcn_exp2f(fmaf(q[r], kli[r], -m[r]));
            o[r] = w0h * (S2[r] - eii * vvi[r]) / S1[r];
        }
        *reinterpret_cast<float2*>(ph + bh + i0) = make_float2(o[0], o[1]);
    }
}

// ---------------------------------------------------------------------------
// One logit per block: recombine layer-3 heads + LN, dot with fc row c.
// grid (NC, NB) = 544 blocks.
// ---------------------------------------------------------------------------
__global__ __launch_bounds__(256) void logits_kernel(
    const float* __restrict__ hprev, const float* __restrict__ php,
    const float* __restrict__ lna, const float* __restrict__ lnb,
    const float* __restrict__ fcw, const float* __restrict__ fcb,
    float* __restrict__ lgt)
{
    __shared__ __align__(16) float arow[G];
    __shared__ float red[8];
    const int c = blockIdx.x, b = blockIdx.y, tid = threadIdx.x;

    const float4* p0 = reinterpret_cast<const float4*>(php + ((size_t)b * NH + 0) * GP);
    const float4* p1 = reinterpret_cast<const float4*>(php + ((size_t)b * NH + 1) * GP);
    const float4* p2 = reinterpret_cast<const float4*>(php + ((size_t)b * NH + 2) * GP);
    const float4* p3 = reinterpret_cast<const float4*>(php + ((size_t)b * NH + 3) * GP);
    const float4* p4 = reinterpret_cast<const float4*>(php + ((size_t)b * NH + 4) * GP);
    float4* ar4 = reinterpret_cast<float4*>(arow);

    float s = 0.f, ss = 0.f;
    for (int k = tid; k < C4; k += 256) {
        float4 a = p0[k], t;
        t = p1[k]; a.x += t.x; a.y += t.y; a.z += t.z; a.w += t.w;
        t = p2[k]; a.x += t.x; a.y += t.y; a.z += t.z; a.w += t.w;
        t = p3[k]; a.x += t.x; a.y += t.y; a.z += t.z; a.w += t.w;
        t = p4[k]; a.x += t.x; a.y += t.y; a.z += t.z; a.w += t.w;
        ar4[k] = a;
        s  += (a.x + a.y) + (a.z + a.w);
        ss += (a.x * a.x + a.y * a.y) + (a.z * a.z + a.w * a.w);
    }
    for (int o = 1; o < 64; o <<= 1) {
        s  += __shfl_xor(s, o);
        ss += __shfl_xor(ss, o);
    }
    if ((tid & 63) == 0) { red[tid >> 6] = s; red[4 + (tid >> 6)] = ss; }
    __syncthreads();
    float S  = (red[0] + red[1]) + (red[2] + red[3]);
    float SS = (red[4] + red[5]) + (red[6] + red[7]);
    const float mean = S / (float)G;
    const float var  = fmaxf((SS - S * mean) / (float)(G - 1), 0.f);
    const float inv  = 1.f / (sqrtf(var) + LN_EPS);

    const float4* hp4 = reinterpret_cast<const float4*>(hprev + (size_t)b * G);
    const float4* ga4 = reinterpret_cast<const float4*>(lna);
    const float4* gb4 = reinterpret_cast<const float4*>(lnb);
    const float4* w4  = reinterpret_cast<const float4*>(fcw + (size_t)c * G);
    float acc = 0.f;
    for (int k = tid; k < C4; k += 256) {
        float4 a = ar4[k], hp = hp4[k], ga = ga4[k], gb = gb4[k], w = w4[k];
        float hx = hp.x + ga.x * (a.x - mean) * inv + gb.x;
        float hy = hp.y + ga.y * (a.y - mean) * inv + gb.y;
        float hz = hp.z + ga.z * (a.z - mean) * inv + gb.z;
        float hw = hp.w + ga.w * (a.w - mean) * inv + gb.w;
        acc += (hx * w.x + hy * w.y) + (hz * w.z + hw * w.w);
    }
    for (int o = 1; o < 64; o <<= 1) acc += __shfl_xor(acc, o);
    __syncthreads();
    if ((tid & 63) == 0) red[tid >> 6] = acc;
    __syncthreads();
    if (tid == 0)
        lgt[(size_t)b * NC + c] =
            (red[0] + red[1]) + (red[2] + red[3]) + fcb[c];
}

// out = log_softmax(logits) — one wave per batch row
__global__ __launch_bounds__(64) void lsm_kernel(
    const float* __restrict__ lgt, float* __restrict__ out)
{
    const int b = blockIdx.x, tid = threadIdx.x;
    float l = (tid < NC) ? lgt[(size_t)b * NC + tid] : -INFINITY;
    float mm = l;
    for (int o = 32; o; o >>= 1) mm = fmaxf(mm, __shfl_xor(mm, o));
    float e = (tid < NC) ? expf(l - mm) : 0.f;
    float se = e;
    for (int o = 32; o; o >>= 1) se += __shfl_xor(se, o);
    if (tid < NC) out[(size_t)b * NC + tid] = l - mm - logf(se);
}

// ---------------------------------------------------------------------------
extern "C" void kernel_launch(void* const* d_in, const int* in_sizes, int n_in,
                              void* d_out, int out_size, void* d_ws, size_t ws_size,
                              hipStream_t stream)
{
    const float* x    = (const float*)d_in[0];
    const float* WQ1  = (const float*)d_in[1];
    const float* WK1  = (const float*)d_in[2];
    const float* WV1  = (const float*)d_in[3];
    const float* W01  = (const float*)d_in[4];
    const float* WQ2  = (const float*)d_in[5];
    const float* WK2  = (const float*)d_in[6];
    const float* WV2  = (const float*)d_in[7];
    const float* W02  = (const float*)d_in[8];
    const float* WQ3  = (const float*)d_in[9];
    const float* WK3  = (const float*)d_in[10];
    const float* WV3  = (const float*)d_in[11];
    const float* W03  = (const float*)d_in[12];
    const float* lna  = (const float*)d_in[13];
    const float* lnb  = (const float*)d_in[14];
    const float* fcw  = (const float*)d_in[15];
    const float* fcb  = (const float*)d_in[16];
    float* out = (float*)d_out;

    const size_t PHS = (size_t)NB * NH * GP;
    float* qt  = (float*)d_ws;           // layer tables
    float* kt  = qt + PHS;
    float* vt  = kt + PHS;
    float* pha = vt + PHS;               // layer 1 / 3 per-head rows
    float* phb = pha + PHS;              // layer 2 per-head rows
    float* h1  = phb + PHS;              // [NB,G] combined input of layer 3
    float* h2  = h1 + (size_t)NB * G;    // [NB,G] combined input of final LN
    float* lgt = h2 + (size_t)NB * G;    // [NB,NC]
    float* kmm = lgt + NB * NC;          // [NB,NH,2]

    const dim3 bgrid(NH, NB);            // 80 blocks
    const dim3 agrid(ICH, NH, NB);       // (54,5,16) = 4320 blocks

    build_layer<true><<<bgrid, 256, 0, stream>>>(
        x, nullptr, lna, lnb, WQ1, WK1, WV1, qt, kt, vt, kmm, nullptr);
    attn_layer<<<agrid, 256, 0, stream>>>(qt, kt, vt, kmm, W01, pha);

    build_layer<false><<<bgrid, 256, 0, stream>>>(
        x, pha, lna, lnb, WQ2, WK2, WV2, qt, kt, vt, kmm, h1);
    attn_layer<<<agrid, 256, 0, stream>>>(qt, kt, vt, kmm, W02, phb);

    build_layer<false><<<bgrid, 256, 0, stream>>>(
        h1, phb, lna, lnb, WQ3, WK3, WV3, qt, kt, vt, kmm, h2);
    attn_layer<<<agrid, 256, 0, stream>>>(qt, kt, vt, kmm, W03, pha);

    // final LN input: residual base h2, layer-3 heads pha
    logits_kernel<<<dim3(NC, NB), 256, 0, stream>>>(
        h2, pha, lna, lnb, fcw, fcb, lgt);
    lsm_kernel<<<NB, 64, 0, stream>>>(lgt, out);
}